// Round 17
// baseline (18504.381 us; speedup 1.0000x reference)
//
#include <hip/hip_runtime.h>

// ---------------------------------------------------------------------------
// 3-layer GCN (PyG gcn_norm semantics) on MI355X.
// MEASUREMENT ROUND (base = R16, 365us): every tail kernel runs REPS
// internal repetitions (determinism preserved) to clear the ~650us
// fillBuffer bar and surface in rocprof top-5. gemm1 untouched.
//   idempotent reps: init_prep, reduce4 (now OUT-OF-PLACE P->H0), p64, p32, psm
//   count_deg: cnt accumulates REPS*deg; scan divides back (exact)
//   fill_csr: dummy cursor2/src2/w2 for reps 0..N-2, real CSR on last rep
// ---------------------------------------------------------------------------

#define REPS_INIT 300
#define REPS_CNT  200
#define REPS_FILL 150
#define REPS_RED  300
#define REPS_P64  80
#define REPS_P32  150
#define REPS_PSM  150

typedef __attribute__((ext_vector_type(8))) short bf16x8;
typedef __attribute__((ext_vector_type(4))) float f32x4;
typedef __attribute__((ext_vector_type(4))) float fv4;

__device__ __forceinline__ float4 ldnt4(const float* p) {
    fv4 v = __builtin_nontemporal_load((const fv4*)p);
    return make_float4(v.x, v.y, v.z, v.w);
}
__device__ __forceinline__ void stnt(float* p, float v) {
    __builtin_nontemporal_store(v, p);
}

__device__ __forceinline__ unsigned cvt_pk_bf16(float a, float b) {
    unsigned r;
    asm("v_cvt_pk_bf16_f32 %0, %1, %2" : "=v"(r) : "v"(a), "v"(b));
    return r;
}

__device__ __forceinline__ void lds_barrier() {
    asm volatile("s_waitcnt lgkmcnt(0)" ::: "memory");
    __builtin_amdgcn_s_barrier();
    asm volatile("" ::: "memory");
}

__device__ __forceinline__ unsigned short f2bf_rne(float f) {
    unsigned u = __float_as_uint(f);
    unsigned r = (u + 0x7FFFu + ((u >> 16) & 1u)) >> 16;
    return (unsigned short)r;
}

// --- fused: zero cnt + probe + W1 split/transpose. REPS_INIT (idempotent).
__global__ void init_prep_k(const int* __restrict__ ei, int* __restrict__ flag,
                            int* __restrict__ cnt, int n,
                            const float* __restrict__ W1,
                            unsigned short* __restrict__ Bt, int K) {
    int t = blockIdx.x * blockDim.x + threadIdx.x;
    for (int rep = 0; rep < REPS_INIT; ++rep) {
        asm volatile("" ::: "memory");
        if (t < n) cnt[t] = 0;
        if (t == 0) {
            int f = 1;
            for (int i = 0; i < 256; ++i) {
                if (ei[2 * i + 1] != 0) { f = 0; break; }
            }
            *flag = f;
        }
        if (t < K * 64) {
            int nn = t & 63, k = t >> 6;
            float f = W1[(size_t)k * 64 + nn];
            unsigned short hi = f2bf_rne(f);
            float hf = __uint_as_float((unsigned)hi << 16);
            unsigned short lo = f2bf_rne(f - hf);
            Bt[(size_t)nn * K + k] = hi;
            Bt[(size_t)64 * K + (size_t)nn * K + k] = lo;
        }
    }
}

__device__ __forceinline__ int edge_val(const int* __restrict__ ei, long long idx, int f64) {
    return f64 ? ei[2 * idx] : ei[(int)idx];
}

// REPS_CNT reps -> cnt = REPS_CNT * deg (scan divides back)
__global__ void count_deg_k(const int* __restrict__ ei, int E, const int* __restrict__ flag,
                            int* __restrict__ cnt) {
    int e = blockIdx.x * blockDim.x + threadIdx.x;
    if (e >= E) return;
    int f = *flag;
    for (int rep = 0; rep < REPS_CNT; ++rep) {
        asm volatile("" ::: "memory");
        int c = edge_val(ei, (long long)E + e, f);
        atomicAdd(&cnt[c], 1);
    }
}

// --- multi-block scan, phase A (divides cnt by REPS_CNT)
__global__ void scan_blk_k(const int* __restrict__ cnt, int* __restrict__ offs,
                           float* __restrict__ dis, int* __restrict__ cursor,
                           int* __restrict__ btot, int n) {
    __shared__ int sh[256];
    const int t = threadIdx.x;
    const int idx = blockIdx.x * 256 + t;
    int v = (idx < n) ? (cnt[idx] / REPS_CNT) : 0;
    sh[t] = v;
    __syncthreads();
    for (int o = 1; o < 256; o <<= 1) {
        int add = (t >= o) ? sh[t - o] : 0;
        __syncthreads();
        sh[t] += add;
        __syncthreads();
    }
    if (idx < n) {
        offs[idx] = sh[t] - v;
        cursor[idx] = 0;
        dis[idx] = rsqrtf((float)(v + 1));  // +1: self loop
    }
    if (t == 255) btot[blockIdx.x] = sh[255];
}

// phase B (fused top-scan + add)
__global__ void scan_add_k(int* __restrict__ offs, const int* __restrict__ btot,
                           int n, int nb) {
    __shared__ int base_sh, tot_sh;
    const int t = threadIdx.x;
    if (t == 0) {
        int base = 0, tot = 0;
        for (int i = 0; i < nb; ++i) {
            int v = btot[i];
            if (i < (int)blockIdx.x) base += v;
            tot += v;
        }
        base_sh = base;
        tot_sh = tot;
    }
    __syncthreads();
    int idx = blockIdx.x * 256 + t;
    if (idx < n) offs[idx] += base_sh;
    if (blockIdx.x == 0 && t == 0) offs[n] = tot_sh;
}

// REPS_FILL: reps 0..N-2 -> dummy cursor2/src2/w2; last rep real.
__global__ void fill_csr_k(const int* __restrict__ ei, int E, const int* __restrict__ flag,
                           const int* __restrict__ offs, int* __restrict__ cursor,
                           int* __restrict__ cursor2,
                           const float* __restrict__ dis, int* __restrict__ src,
                           float* __restrict__ w, int* __restrict__ src2,
                           float* __restrict__ w2) {
    int e = blockIdx.x * blockDim.x + threadIdx.x;
    if (e >= E) return;
    int f = *flag;
    for (int rep = 0; rep < REPS_FILL; ++rep) {
        asm volatile("" ::: "memory");
        int r = edge_val(ei, (long long)e, f);
        int c = edge_val(ei, (long long)E + e, f);
        bool last = (rep == REPS_FILL - 1);
        int* cur = last ? cursor : cursor2;
        int* so = last ? src : src2;
        float* wo = last ? w : w2;
        int pos = offs[c] + atomicAdd(&cur[c], 1);
        so[pos] = r;
        wo[pos] = dis[r] * dis[c];
    }
}

// --- GEMM1 (R16 exact): BM=128, BK=32, K-split x4, lgkm-only barriers.
__global__ __launch_bounds__(256) void gemm1_mfma_k(
    const float* __restrict__ A, const unsigned short* __restrict__ Bt,
    float* __restrict__ P, int n, int K, int kchunk) {
    __shared__ unsigned short As[2][128][40];
    const int tid = threadIdx.x;
    const int lane = tid & 63;
    const int wid = tid >> 6;
    const int wm = wid >> 1, wn = wid & 1;
    const int lrow = lane & 15, lkh = lane >> 4;
    const int bid = blockIdx.x;
    const int by = (bid & 7) >> 1;
    const int bx = ((bid >> 3) << 1) | (bid & 1);
    const int bm = bx * 128;
    const int k0 = by * kchunk;
    const int iters = kchunk / 32;

    const unsigned short* Bh = Bt;
    const unsigned short* Bl = Bt + (size_t)64 * K;

    f32x4 acc[4][2] = {};
    float4 st[4];

    auto loadA = [&](int kt) {
#pragma unroll
        for (int i = 0; i < 4; ++i) {
            int v = tid + i * 256;
            int r = v >> 3, c = (v & 7) * 4;
            st[i] = ldnt4(A + (size_t)(bm + r) * K + k0 + kt * 32 + c);
        }
    };

    loadA(0);
    for (int kt = 0; kt < iters; ++kt) {
        bf16x8 bh[2], bl[2];
#pragma unroll
        for (int nf = 0; nf < 2; ++nf) {
            int brow = wn * 32 + nf * 16 + lrow;
            size_t bo = (size_t)brow * K + k0 + kt * 32 + lkh * 8;
            bh[nf] = *(const bf16x8*)(Bh + bo);
            bl[nf] = *(const bf16x8*)(Bl + bo);
        }
#pragma unroll
        for (int i = 0; i < 4; ++i) {
            int v = tid + i * 256;
            int r = v >> 3, c = (v & 7) * 4;
            float f0 = st[i].x, f1 = st[i].y, f2 = st[i].z, f3 = st[i].w;
            unsigned h01 = cvt_pk_bf16(f0, f1);
            unsigned h23 = cvt_pk_bf16(f2, f3);
            float r0 = f0 - __uint_as_float(h01 << 16);
            float r1 = f1 - __uint_as_float(h01 & 0xFFFF0000u);
            float r2 = f2 - __uint_as_float(h23 << 16);
            float r3 = f3 - __uint_as_float(h23 & 0xFFFF0000u);
            unsigned l01 = cvt_pk_bf16(r0, r1);
            unsigned l23 = cvt_pk_bf16(r2, r3);
            *(uint2*)&As[0][r][c] = make_uint2(h01, h23);
            *(uint2*)&As[1][r][c] = make_uint2(l01, l23);
        }
        lds_barrier();
        if (kt + 1 < iters) loadA(kt + 1);
        bf16x8 ah[4], al[4];
#pragma unroll
        for (int mf = 0; mf < 4; ++mf) {
            int row = wm * 64 + mf * 16 + lrow;
            ah[mf] = *(const bf16x8*)&As[0][row][lkh * 8];
            al[mf] = *(const bf16x8*)&As[1][row][lkh * 8];
        }
#pragma unroll
        for (int mf = 0; mf < 4; ++mf)
#pragma unroll
            for (int nf = 0; nf < 2; ++nf) {
                acc[mf][nf] = __builtin_amdgcn_mfma_f32_16x16x32_bf16(ah[mf], bh[nf], acc[mf][nf], 0, 0, 0);
                acc[mf][nf] = __builtin_amdgcn_mfma_f32_16x16x32_bf16(al[mf], bh[nf], acc[mf][nf], 0, 0, 0);
                acc[mf][nf] = __builtin_amdgcn_mfma_f32_16x16x32_bf16(ah[mf], bl[nf], acc[mf][nf], 0, 0, 0);
            }
        lds_barrier();
    }
    float* out = P + (size_t)by * n * 64;
#pragma unroll
    for (int mf = 0; mf < 4; ++mf)
#pragma unroll
        for (int nf = 0; nf < 2; ++nf)
#pragma unroll
            for (int j = 0; j < 4; ++j) {
                int row = bm + wm * 64 + mf * 16 + lkh * 4 + j;
                int col = wn * 32 + nf * 16 + lrow;
                stnt(out + (size_t)row * 64 + col, acc[mf][nf][j]);
            }
}

// OUT-OF-PLACE reduce (idempotent): H0 = sum of 4 planes of P. REPS_RED.
__global__ void reduce4o_k(const float4* __restrict__ p, float4* __restrict__ h0,
                           size_t q) {
    size_t i = (size_t)blockIdx.x * blockDim.x + threadIdx.x;
    if (i >= q) return;
    for (int rep = 0; rep < REPS_RED; ++rep) {
        asm volatile("" ::: "memory");
        float4 a = p[i];
#pragma unroll
        for (int z = 1; z < 4; ++z) {
            float4 b = ldnt4((const float*)(p + i + (size_t)z * q));
            a.x += b.x; a.y += b.y; a.z += b.z; a.w += b.w;
        }
        h0[i] = a;
    }
}

// --- fused: H1 = relu(Agg(H0)+b1) ; H2a = H1 @ W2. REPS_P64 (idempotent).
__global__ __launch_bounds__(256) void prop64_gemm2_k(
    const float* __restrict__ h, const int* __restrict__ offs,
    const int* __restrict__ src, const float* __restrict__ w,
    const float* __restrict__ dis, const float* __restrict__ b1,
    const float* __restrict__ W2, float* __restrict__ H2a, int n) {
    __shared__ float Ws[64 * 32];
    __shared__ float rows[16][68];
    const int tid = threadIdx.x;
    for (int i = tid; i < 64 * 32; i += 256) Ws[i] = W2[i];
    const int t = blockIdx.x * 256 + tid;
    const int node = t >> 4, q = t & 15, nl = tid >> 4;
    for (int rep = 0; rep < REPS_P64; ++rep) {
        asm volatile("" ::: "memory");
        float4 acc = make_float4(0.f, 0.f, 0.f, 0.f);
        int p0 = offs[node], p1 = offs[node + 1];
        for (int p = p0; p < p1; ++p) {
            float ww = w[p];
            float4 hv = *(const float4*)(h + (size_t)src[p] * 64 + q * 4);
            acc.x = fmaf(ww, hv.x, acc.x);
            acc.y = fmaf(ww, hv.y, acc.y);
            acc.z = fmaf(ww, hv.z, acc.z);
            acc.w = fmaf(ww, hv.w, acc.w);
        }
        float d = dis[node];
        float ds = d * d;
        float4 hv = *(const float4*)(h + (size_t)node * 64 + q * 4);
        float4 bv = *(const float4*)(b1 + q * 4);
        acc.x = fmaxf(fmaf(ds, hv.x, acc.x) + bv.x, 0.f);
        acc.y = fmaxf(fmaf(ds, hv.y, acc.y) + bv.y, 0.f);
        acc.z = fmaxf(fmaf(ds, hv.z, acc.z) + bv.z, 0.f);
        acc.w = fmaxf(fmaf(ds, hv.w, acc.w) + bv.w, 0.f);
        *(float4*)&rows[nl][q * 4] = acc;
        __syncthreads();
        const int c0 = q * 2;
        float s0 = 0.f, s1 = 0.f;
#pragma unroll
        for (int k = 0; k < 64; ++k) {
            float v = rows[nl][k];
            s0 = fmaf(v, Ws[k * 32 + c0], s0);
            s1 = fmaf(v, Ws[k * 32 + c0 + 1], s1);
        }
        H2a[(size_t)node * 32 + c0] = s0;
        H2a[(size_t)node * 32 + c0 + 1] = s1;
        __syncthreads();
    }
}

// --- fused: H2 = relu(Agg(H2a)+b2) ; H3a = H2 @ W3. REPS_P32 (idempotent).
__global__ __launch_bounds__(256) void prop32_gemm3_k(
    const float* __restrict__ h, const int* __restrict__ offs,
    const int* __restrict__ src, const float* __restrict__ w,
    const float* __restrict__ dis, const float* __restrict__ b2,
    const float* __restrict__ W3, float* __restrict__ H3a, int n) {
    __shared__ float Ws[32 * 16];
    __shared__ float rows[32][36];
    const int tid = threadIdx.x;
    for (int i = tid; i < 32 * 16; i += 256) Ws[i] = W3[i];
    const int t = blockIdx.x * 256 + tid;
    const int node = t >> 3, q = t & 7, nl = tid >> 3;
    for (int rep = 0; rep < REPS_P32; ++rep) {
        asm volatile("" ::: "memory");
        float4 acc = make_float4(0.f, 0.f, 0.f, 0.f);
        int p0 = offs[node], p1 = offs[node + 1];
        for (int p = p0; p < p1; ++p) {
            float ww = w[p];
            float4 hv = *(const float4*)(h + (size_t)src[p] * 32 + q * 4);
            acc.x = fmaf(ww, hv.x, acc.x);
            acc.y = fmaf(ww, hv.y, acc.y);
            acc.z = fmaf(ww, hv.z, acc.z);
            acc.w = fmaf(ww, hv.w, acc.w);
        }
        float d = dis[node];
        float ds = d * d;
        float4 hv = *(const float4*)(h + (size_t)node * 32 + q * 4);
        float4 bv = *(const float4*)(b2 + q * 4);
        acc.x = fmaxf(fmaf(ds, hv.x, acc.x) + bv.x, 0.f);
        acc.y = fmaxf(fmaf(ds, hv.y, acc.y) + bv.y, 0.f);
        acc.z = fmaxf(fmaf(ds, hv.z, acc.z) + bv.z, 0.f);
        acc.w = fmaxf(fmaf(ds, hv.w, acc.w) + bv.w, 0.f);
        *(float4*)&rows[nl][q * 4] = acc;
        __syncthreads();
        const int c0 = q * 2;
        float s0 = 0.f, s1 = 0.f;
#pragma unroll
        for (int k = 0; k < 32; ++k) {
            float v = rows[nl][k];
            s0 = fmaf(v, Ws[k * 16 + c0], s0);
            s1 = fmaf(v, Ws[k * 16 + c0 + 1], s1);
        }
        H3a[(size_t)node * 16 + c0] = s0;
        H3a[(size_t)node * 16 + c0 + 1] = s1;
        __syncthreads();
    }
}

// --- final propagate + softmax. REPS_PSM (idempotent, pure).
__global__ void prop_softmax_k(const float* __restrict__ h, const int* __restrict__ offs,
                               const int* __restrict__ src, const float* __restrict__ w,
                               const float* __restrict__ dis, const float* __restrict__ b,
                               float* __restrict__ out, int n) {
    int t = blockIdx.x * blockDim.x + threadIdx.x;
    int node = t >> 2, q = t & 3;
    if (node >= n) return;
    for (int rep = 0; rep < REPS_PSM; ++rep) {
        asm volatile("" ::: "memory");
        float4 acc = make_float4(0.f, 0.f, 0.f, 0.f);
        int p0 = offs[node], p1 = offs[node + 1];
        for (int p = p0; p < p1; ++p) {
            float ww = w[p];
            float4 hv = *(const float4*)(h + (size_t)src[p] * 16 + q * 4);
            acc.x = fmaf(ww, hv.x, acc.x);
            acc.y = fmaf(ww, hv.y, acc.y);
            acc.z = fmaf(ww, hv.z, acc.z);
            acc.w = fmaf(ww, hv.w, acc.w);
        }
        float d = dis[node];
        float ds = d * d;
        float4 hv = *(const float4*)(h + (size_t)node * 16 + q * 4);
        float4 bv = *(const float4*)(b + q * 4);
        acc.x = fmaf(ds, hv.x, acc.x) + bv.x;
        acc.y = fmaf(ds, hv.y, acc.y) + bv.y;
        acc.z = fmaf(ds, hv.z, acc.z) + bv.z;
        acc.w = fmaf(ds, hv.w, acc.w) + bv.w;
        float m = fmaxf(fmaxf(acc.x, acc.y), fmaxf(acc.z, acc.w));
        m = fmaxf(m, __shfl_xor(m, 1));
        m = fmaxf(m, __shfl_xor(m, 2));
        float4 e;
        e.x = __expf(acc.x - m);
        e.y = __expf(acc.y - m);
        e.z = __expf(acc.z - m);
        e.w = __expf(acc.w - m);
        float s = e.x + e.y + e.z + e.w;
        s += __shfl_xor(s, 1);
        s += __shfl_xor(s, 2);
        float inv = 1.f / s;
        e.x *= inv; e.y *= inv; e.z *= inv; e.w *= inv;
        *(float4*)(out + (size_t)node * 16 + q * 4) = e;
    }
}

extern "C" void kernel_launch(void* const* d_in, const int* in_sizes, int n_in,
                              void* d_out, int out_size, void* d_ws, size_t ws_size,
                              hipStream_t stream) {
    const float* x  = (const float*)d_in[0];
    const int*   ei = (const int*)d_in[1];
    const float* W1 = (const float*)d_in[2];
    const float* b1 = (const float*)d_in[3];
    const float* W2 = (const float*)d_in[4];
    const float* b2 = (const float*)d_in[5];
    const float* W3 = (const float*)d_in[6];
    const float* b3 = (const float*)d_in[7];
    float* out = (float*)d_out;

    const int n = in_sizes[2] / 64;
    const int K = in_sizes[0] / n;
    const int E = in_sizes[1] / 2;
    const int nb = (n + 255) / 256;

    char* ws = (char*)d_ws;
    size_t off = 0;
    auto alloc = [&](size_t bytes) {
        char* p = ws + off;
        off = (off + bytes + 255) & ~(size_t)255;
        return p;
    };
    int*   flag    = (int*)  alloc(4);
    int*   cnt     = (int*)  alloc((size_t)n * 4);
    int*   cursor  = (int*)  alloc((size_t)n * 4);
    int*   cursor2 = (int*)  alloc((size_t)n * 4);
    int*   offs    = (int*)  alloc((size_t)(n + 1) * 4);
    int*   btot    = (int*)  alloc((size_t)nb * 4);
    float* dis     = (float*)alloc((size_t)n * 4);
    int*   csrs    = (int*)  alloc((size_t)E * 4);
    float* csrw    = (float*)alloc((size_t)E * 4);
    int*   src2    = (int*)  alloc((size_t)(E + 32768) * 4);
    float* w2      = (float*)alloc((size_t)(E + 32768) * 4);
    unsigned short* Btw = (unsigned short*)alloc((size_t)2 * 64 * K * 2);
    float* P       = (float*)alloc((size_t)4 * n * 64 * 4);
    float* H0      = (float*)alloc((size_t)n * 64 * 4);
    float* H2a     = (float*)alloc((size_t)n * 32 * 4);
    float* H3a     = (float*)alloc((size_t)n * 16 * 4);
    (void)ws_size; (void)n_in; (void)out_size;

    hipMemsetAsync(cursor2, 0, (size_t)n * 4, stream);
    init_prep_k<<<(K * 64 + 255) / 256, 256, 0, stream>>>(ei, flag, cnt, n, W1, Btw, K);
    count_deg_k<<<(E + 255) / 256, 256, 0, stream>>>(ei, E, flag, cnt);
    scan_blk_k<<<nb, 256, 0, stream>>>(cnt, offs, dis, cursor, btot, n);
    scan_add_k<<<nb, 256, 0, stream>>>(offs, btot, n, nb);
    fill_csr_k<<<(E + 255) / 256, 256, 0, stream>>>(ei, E, flag, offs, cursor, cursor2,
                                                    dis, csrs, csrw, src2, w2);

    gemm1_mfma_k<<<(n / 128) * 4, 256, 0, stream>>>(x, Btw, P, n, K, K / 4);
    size_t q = (size_t)n * 64 / 4;
    reduce4o_k<<<(int)((q + 255) / 256), 256, 0, stream>>>((const float4*)P, (float4*)H0, q);

    prop64_gemm2_k<<<n * 16 / 256, 256, 0, stream>>>(H0, offs, csrs, csrw, dis, b1, W2, H2a, n);
    prop32_gemm3_k<<<n * 8 / 256, 256, 0, stream>>>(H2a, offs, csrs, csrw, dis, b2, W3, H3a, n);
    prop_softmax_k<<<n * 4 / 256, 256, 0, stream>>>(H3a, offs, csrs, csrw, dis, b3, out, n);
}

// Round 18
// 355.369 us; speedup vs baseline: 52.0710x; 52.0710x over previous
//
#include <hip/hip_runtime.h>

// ---------------------------------------------------------------------------
// 3-layer GCN (PyG gcn_norm semantics) on MI355X.
// R18 = R16 (best, 365us) with the CSR build de-contended (R17 measured
// count=28us, fill~50us, both atomic-serialization-bound):
//   - cnt replicated 4x (plane = e&3): per-cacheline RMW serialization /4
//   - scan_add builds base4[r][c] = offs[c] + prefix of planes -> fill's
//     atomic cursor is also 4-way replicated, positions exact & disjoint
//   - CSR packed as 8B records (w|src): 1 scattered store in fill,
//     1 load in the props (was 2 each)
// gemm1 (R16 lgkm-barrier), scans, fused tail otherwise unchanged.
// ---------------------------------------------------------------------------

typedef __attribute__((ext_vector_type(8))) short bf16x8;
typedef __attribute__((ext_vector_type(4))) float f32x4;
typedef __attribute__((ext_vector_type(4))) float fv4;

__device__ __forceinline__ float4 ldnt4(const float* p) {
    fv4 v = __builtin_nontemporal_load((const fv4*)p);
    return make_float4(v.x, v.y, v.z, v.w);
}
__device__ __forceinline__ void stnt(float* p, float v) {
    __builtin_nontemporal_store(v, p);
}

__device__ __forceinline__ unsigned cvt_pk_bf16(float a, float b) {
    unsigned r;
    asm("v_cvt_pk_bf16_f32 %0, %1, %2" : "=v"(r) : "v"(a), "v"(b));
    return r;
}

__device__ __forceinline__ void lds_barrier() {
    asm volatile("s_waitcnt lgkmcnt(0)" ::: "memory");
    __builtin_amdgcn_s_barrier();
    asm volatile("" ::: "memory");
}

__device__ __forceinline__ unsigned short f2bf_rne(float f) {
    unsigned u = __float_as_uint(f);
    unsigned r = (u + 0x7FFFu + ((u >> 16) & 1u)) >> 16;
    return (unsigned short)r;
}

// --- fused: zero cnt (4 planes) + int64-vs-int32 probe + W1 split/transpose
__global__ void init_prep_k(const int* __restrict__ ei, int* __restrict__ flag,
                            int* __restrict__ cnt, int n,
                            const float* __restrict__ W1,
                            unsigned short* __restrict__ Bt, int K) {
    int t = blockIdx.x * blockDim.x + threadIdx.x;
    if (t < 4 * n) cnt[t] = 0;
    if (t == 0) {
        int f = 1;
        for (int i = 0; i < 256; ++i) {
            if (ei[2 * i + 1] != 0) { f = 0; break; }
        }
        *flag = f;
    }
    if (t < K * 64) {
        int nn = t & 63, k = t >> 6;
        float f = W1[(size_t)k * 64 + nn];
        unsigned short hi = f2bf_rne(f);
        float hf = __uint_as_float((unsigned)hi << 16);
        unsigned short lo = f2bf_rne(f - hf);
        Bt[(size_t)nn * K + k] = hi;
        Bt[(size_t)64 * K + (size_t)nn * K + k] = lo;
    }
}

__device__ __forceinline__ int edge_val(const int* __restrict__ ei, long long idx, int f64) {
    return f64 ? ei[2 * idx] : ei[(int)idx];
}

// count into plane e&3 -> 4x less per-line RMW serialization
__global__ void count_deg_k(const int* __restrict__ ei, int E, const int* __restrict__ flag,
                            int* __restrict__ cnt, int n) {
    int e = blockIdx.x * blockDim.x + threadIdx.x;
    if (e >= E) return;
    int f = *flag;
    int c = edge_val(ei, (long long)E + e, f);
    atomicAdd(&cnt[(e & 3) * n + c], 1);
}

// --- scan phase A: per-block exclusive scan of node totals (sum of 4 planes)
//     + dis = rsqrt(deg+1).
__global__ void scan_blk_k(const int* __restrict__ cnt, int* __restrict__ offs,
                           float* __restrict__ dis, int* __restrict__ btot, int n) {
    __shared__ int sh[256];
    const int t = threadIdx.x;
    const int idx = blockIdx.x * 256 + t;
    int v = 0;
    if (idx < n) {
#pragma unroll
        for (int r = 0; r < 4; ++r) v += cnt[r * n + idx];
    }
    sh[t] = v;
    __syncthreads();
    for (int o = 1; o < 256; o <<= 1) {
        int add = (t >= o) ? sh[t - o] : 0;
        __syncthreads();
        sh[t] += add;
        __syncthreads();
    }
    if (idx < n) {
        offs[idx] = sh[t] - v;  // exclusive local prefix
        dis[idx] = rsqrtf((float)(v + 1));  // +1: self loop
    }
    if (t == 255) btot[blockIdx.x] = sh[255];
}

// phase B: finalize offs; build per-plane cursor bases
//   base4[r][c] = offs[c] + sum_{r'<r} cnt[r'][c]
__global__ void scan_add_k(int* __restrict__ offs, const int* __restrict__ btot,
                           const int* __restrict__ cnt, int* __restrict__ base4,
                           int n, int nb) {
    __shared__ int base_sh, tot_sh;
    const int t = threadIdx.x;
    if (t == 0) {
        int base = 0, tot = 0;
        for (int i = 0; i < nb; ++i) {
            int v = btot[i];
            if (i < (int)blockIdx.x) base += v;
            tot += v;
        }
        base_sh = base;
        tot_sh = tot;
    }
    __syncthreads();
    int idx = blockIdx.x * 256 + t;
    if (idx < n) {
        int o = offs[idx] + base_sh;
        offs[idx] = o;
        int b = o;
#pragma unroll
        for (int r = 0; r < 4; ++r) {
            base4[r * n + idx] = b;
            b += cnt[r * n + idx];
        }
    }
    if (blockIdx.x == 0 && t == 0) offs[n] = tot_sh;
}

// fill packed CSR records: csr8[pos] = (f32bits(w)<<32) | src
__global__ void fill_csr_k(const int* __restrict__ ei, int E, const int* __restrict__ flag,
                           int* __restrict__ base4,
                           const float* __restrict__ dis,
                           unsigned long long* __restrict__ csr8, int n) {
    int e = blockIdx.x * blockDim.x + threadIdx.x;
    if (e >= E) return;
    int f = *flag;
    int r = edge_val(ei, (long long)e, f);
    int c = edge_val(ei, (long long)E + e, f);
    int pos = atomicAdd(&base4[(e & 3) * n + c], 1);
    float w = dis[r] * dis[c];
    unsigned long long rec = ((unsigned long long)__float_as_uint(w) << 32) | (unsigned)r;
    csr8[pos] = rec;
}

// --- GEMM1 (R16 exact): BM=128, BK=32, K-split x4, lgkm-only barriers.
__global__ __launch_bounds__(256) void gemm1_mfma_k(
    const float* __restrict__ A, const unsigned short* __restrict__ Bt,
    float* __restrict__ P, int n, int K, int kchunk) {
    __shared__ unsigned short As[2][128][40];
    const int tid = threadIdx.x;
    const int lane = tid & 63;
    const int wid = tid >> 6;
    const int wm = wid >> 1, wn = wid & 1;
    const int lrow = lane & 15, lkh = lane >> 4;
    const int bid = blockIdx.x;
    const int by = (bid & 7) >> 1;
    const int bx = ((bid >> 3) << 1) | (bid & 1);
    const int bm = bx * 128;
    const int k0 = by * kchunk;
    const int iters = kchunk / 32;

    const unsigned short* Bh = Bt;
    const unsigned short* Bl = Bt + (size_t)64 * K;

    f32x4 acc[4][2] = {};
    float4 st[4];

    auto loadA = [&](int kt) {
#pragma unroll
        for (int i = 0; i < 4; ++i) {
            int v = tid + i * 256;
            int r = v >> 3, c = (v & 7) * 4;
            st[i] = ldnt4(A + (size_t)(bm + r) * K + k0 + kt * 32 + c);
        }
    };

    loadA(0);
    for (int kt = 0; kt < iters; ++kt) {
        bf16x8 bh[2], bl[2];
#pragma unroll
        for (int nf = 0; nf < 2; ++nf) {
            int brow = wn * 32 + nf * 16 + lrow;
            size_t bo = (size_t)brow * K + k0 + kt * 32 + lkh * 8;
            bh[nf] = *(const bf16x8*)(Bh + bo);
            bl[nf] = *(const bf16x8*)(Bl + bo);
        }
#pragma unroll
        for (int i = 0; i < 4; ++i) {
            int v = tid + i * 256;
            int r = v >> 3, c = (v & 7) * 4;
            float f0 = st[i].x, f1 = st[i].y, f2 = st[i].z, f3 = st[i].w;
            unsigned h01 = cvt_pk_bf16(f0, f1);
            unsigned h23 = cvt_pk_bf16(f2, f3);
            float r0 = f0 - __uint_as_float(h01 << 16);
            float r1 = f1 - __uint_as_float(h01 & 0xFFFF0000u);
            float r2 = f2 - __uint_as_float(h23 << 16);
            float r3 = f3 - __uint_as_float(h23 & 0xFFFF0000u);
            unsigned l01 = cvt_pk_bf16(r0, r1);
            unsigned l23 = cvt_pk_bf16(r2, r3);
            *(uint2*)&As[0][r][c] = make_uint2(h01, h23);
            *(uint2*)&As[1][r][c] = make_uint2(l01, l23);
        }
        lds_barrier();
        if (kt + 1 < iters) loadA(kt + 1);
        bf16x8 ah[4], al[4];
#pragma unroll
        for (int mf = 0; mf < 4; ++mf) {
            int row = wm * 64 + mf * 16 + lrow;
            ah[mf] = *(const bf16x8*)&As[0][row][lkh * 8];
            al[mf] = *(const bf16x8*)&As[1][row][lkh * 8];
        }
#pragma unroll
        for (int mf = 0; mf < 4; ++mf)
#pragma unroll
            for (int nf = 0; nf < 2; ++nf) {
                acc[mf][nf] = __builtin_amdgcn_mfma_f32_16x16x32_bf16(ah[mf], bh[nf], acc[mf][nf], 0, 0, 0);
                acc[mf][nf] = __builtin_amdgcn_mfma_f32_16x16x32_bf16(al[mf], bh[nf], acc[mf][nf], 0, 0, 0);
                acc[mf][nf] = __builtin_amdgcn_mfma_f32_16x16x32_bf16(ah[mf], bl[nf], acc[mf][nf], 0, 0, 0);
            }
        lds_barrier();
    }
    float* out = P + (size_t)by * n * 64;
#pragma unroll
    for (int mf = 0; mf < 4; ++mf)
#pragma unroll
        for (int nf = 0; nf < 2; ++nf)
#pragma unroll
            for (int j = 0; j < 4; ++j) {
                int row = bm + wm * 64 + mf * 16 + lkh * 4 + j;
                int col = wn * 32 + nf * 16 + lrow;
                stnt(out + (size_t)row * 64 + col, acc[mf][nf][j]);
            }
}

__global__ void reduce4_k(float4* __restrict__ p, size_t q) {
    size_t i = (size_t)blockIdx.x * blockDim.x + threadIdx.x;
    if (i >= q) return;
    float4 a = p[i];
#pragma unroll
    for (int z = 1; z < 4; ++z) {
        float4 b = ldnt4((const float*)(p + i + (size_t)z * q));
        a.x += b.x; a.y += b.y; a.z += b.z; a.w += b.w;
    }
    p[i] = a;
}

// --- fused: H1 = relu(Agg(H0)+b1) ; H2a = H1 @ W2.  16 thr/node.
__global__ __launch_bounds__(256) void prop64_gemm2_k(
    const float* __restrict__ h, const int* __restrict__ offs,
    const int2* __restrict__ csr8,
    const float* __restrict__ dis, const float* __restrict__ b1,
    const float* __restrict__ W2, float* __restrict__ H2a, int n) {
    __shared__ float Ws[64 * 32];
    __shared__ float rows[16][68];
    const int tid = threadIdx.x;
    for (int i = tid; i < 64 * 32; i += 256) Ws[i] = W2[i];
    const int t = blockIdx.x * 256 + tid;
    const int node = t >> 4, q = t & 15, nl = tid >> 4;
    float4 acc = make_float4(0.f, 0.f, 0.f, 0.f);
    int p0 = offs[node], p1 = offs[node + 1];
    for (int p = p0; p < p1; ++p) {
        int2 rec = csr8[p];
        float ww = __int_as_float(rec.y);
        float4 hv = *(const float4*)(h + (size_t)rec.x * 64 + q * 4);
        acc.x = fmaf(ww, hv.x, acc.x);
        acc.y = fmaf(ww, hv.y, acc.y);
        acc.z = fmaf(ww, hv.z, acc.z);
        acc.w = fmaf(ww, hv.w, acc.w);
    }
    float d = dis[node];
    float ds = d * d;
    float4 hv = *(const float4*)(h + (size_t)node * 64 + q * 4);
    float4 bv = *(const float4*)(b1 + q * 4);
    acc.x = fmaxf(fmaf(ds, hv.x, acc.x) + bv.x, 0.f);
    acc.y = fmaxf(fmaf(ds, hv.y, acc.y) + bv.y, 0.f);
    acc.z = fmaxf(fmaf(ds, hv.z, acc.z) + bv.z, 0.f);
    acc.w = fmaxf(fmaf(ds, hv.w, acc.w) + bv.w, 0.f);
    *(float4*)&rows[nl][q * 4] = acc;
    __syncthreads();
    const int c0 = q * 2;
    float s0 = 0.f, s1 = 0.f;
#pragma unroll
    for (int k = 0; k < 64; ++k) {
        float v = rows[nl][k];
        s0 = fmaf(v, Ws[k * 32 + c0], s0);
        s1 = fmaf(v, Ws[k * 32 + c0 + 1], s1);
    }
    H2a[(size_t)node * 32 + c0] = s0;
    H2a[(size_t)node * 32 + c0 + 1] = s1;
}

// --- fused: H2 = relu(Agg(H2a)+b2) ; H3a = H2 @ W3.  8 thr/node.
__global__ __launch_bounds__(256) void prop32_gemm3_k(
    const float* __restrict__ h, const int* __restrict__ offs,
    const int2* __restrict__ csr8,
    const float* __restrict__ dis, const float* __restrict__ b2,
    const float* __restrict__ W3, float* __restrict__ H3a, int n) {
    __shared__ float Ws[32 * 16];
    __shared__ float rows[32][36];
    const int tid = threadIdx.x;
    for (int i = tid; i < 32 * 16; i += 256) Ws[i] = W3[i];
    const int t = blockIdx.x * 256 + tid;
    const int node = t >> 3, q = t & 7, nl = tid >> 3;
    float4 acc = make_float4(0.f, 0.f, 0.f, 0.f);
    int p0 = offs[node], p1 = offs[node + 1];
    for (int p = p0; p < p1; ++p) {
        int2 rec = csr8[p];
        float ww = __int_as_float(rec.y);
        float4 hv = *(const float4*)(h + (size_t)rec.x * 32 + q * 4);
        acc.x = fmaf(ww, hv.x, acc.x);
        acc.y = fmaf(ww, hv.y, acc.y);
        acc.z = fmaf(ww, hv.z, acc.z);
        acc.w = fmaf(ww, hv.w, acc.w);
    }
    float d = dis[node];
    float ds = d * d;
    float4 hv = *(const float4*)(h + (size_t)node * 32 + q * 4);
    float4 bv = *(const float4*)(b2 + q * 4);
    acc.x = fmaxf(fmaf(ds, hv.x, acc.x) + bv.x, 0.f);
    acc.y = fmaxf(fmaf(ds, hv.y, acc.y) + bv.y, 0.f);
    acc.z = fmaxf(fmaf(ds, hv.z, acc.z) + bv.z, 0.f);
    acc.w = fmaxf(fmaf(ds, hv.w, acc.w) + bv.w, 0.f);
    *(float4*)&rows[nl][q * 4] = acc;
    __syncthreads();
    const int c0 = q * 2;
    float s0 = 0.f, s1 = 0.f;
#pragma unroll
    for (int k = 0; k < 32; ++k) {
        float v = rows[nl][k];
        s0 = fmaf(v, Ws[k * 16 + c0], s0);
        s1 = fmaf(v, Ws[k * 16 + c0 + 1], s1);
    }
    H3a[(size_t)node * 16 + c0] = s0;
    H3a[(size_t)node * 16 + c0 + 1] = s1;
}

// --- final propagate (F=16) + bias + softmax, float4/thread, 4 lanes/node
__global__ void prop_softmax_k(const float* __restrict__ h, const int* __restrict__ offs,
                               const int2* __restrict__ csr8,
                               const float* __restrict__ dis, const float* __restrict__ b,
                               float* __restrict__ out, int n) {
    int t = blockIdx.x * blockDim.x + threadIdx.x;
    int node = t >> 2, q = t & 3;
    if (node >= n) return;
    float4 acc = make_float4(0.f, 0.f, 0.f, 0.f);
    int p0 = offs[node], p1 = offs[node + 1];
    for (int p = p0; p < p1; ++p) {
        int2 rec = csr8[p];
        float ww = __int_as_float(rec.y);
        float4 hv = *(const float4*)(h + (size_t)rec.x * 16 + q * 4);
        acc.x = fmaf(ww, hv.x, acc.x);
        acc.y = fmaf(ww, hv.y, acc.y);
        acc.z = fmaf(ww, hv.z, acc.z);
        acc.w = fmaf(ww, hv.w, acc.w);
    }
    float d = dis[node];
    float ds = d * d;
    float4 hv = *(const float4*)(h + (size_t)node * 16 + q * 4);
    float4 bv = *(const float4*)(b + q * 4);
    acc.x = fmaf(ds, hv.x, acc.x) + bv.x;
    acc.y = fmaf(ds, hv.y, acc.y) + bv.y;
    acc.z = fmaf(ds, hv.z, acc.z) + bv.z;
    acc.w = fmaf(ds, hv.w, acc.w) + bv.w;
    float m = fmaxf(fmaxf(acc.x, acc.y), fmaxf(acc.z, acc.w));
    m = fmaxf(m, __shfl_xor(m, 1));
    m = fmaxf(m, __shfl_xor(m, 2));
    float4 e;
    e.x = __expf(acc.x - m);
    e.y = __expf(acc.y - m);
    e.z = __expf(acc.z - m);
    e.w = __expf(acc.w - m);
    float s = e.x + e.y + e.z + e.w;
    s += __shfl_xor(s, 1);
    s += __shfl_xor(s, 2);
    float inv = 1.f / s;
    e.x *= inv; e.y *= inv; e.z *= inv; e.w *= inv;
    *(float4*)(out + (size_t)node * 16 + q * 4) = e;
}

extern "C" void kernel_launch(void* const* d_in, const int* in_sizes, int n_in,
                              void* d_out, int out_size, void* d_ws, size_t ws_size,
                              hipStream_t stream) {
    const float* x  = (const float*)d_in[0];
    const int*   ei = (const int*)d_in[1];
    const float* W1 = (const float*)d_in[2];
    const float* b1 = (const float*)d_in[3];
    const float* W2 = (const float*)d_in[4];
    const float* b2 = (const float*)d_in[5];
    const float* W3 = (const float*)d_in[6];
    const float* b3 = (const float*)d_in[7];
    float* out = (float*)d_out;

    const int n = in_sizes[2] / 64;
    const int K = in_sizes[0] / n;
    const int E = in_sizes[1] / 2;
    const int nb = (n + 255) / 256;

    char* ws = (char*)d_ws;
    size_t off = 0;
    auto alloc = [&](size_t bytes) {
        char* p = ws + off;
        off = (off + bytes + 255) & ~(size_t)255;
        return p;
    };
    int*   flag   = (int*)  alloc(4);
    int*   cnt    = (int*)  alloc((size_t)4 * n * 4);
    int*   base4  = (int*)  alloc((size_t)4 * n * 4);
    int*   offs   = (int*)  alloc((size_t)(n + 1) * 4);
    int*   btot   = (int*)  alloc((size_t)nb * 4);
    float* dis    = (float*)alloc((size_t)n * 4);
    unsigned long long* csr8 = (unsigned long long*)alloc((size_t)E * 8);
    unsigned short* Btw = (unsigned short*)alloc((size_t)2 * 64 * K * 2);
    float* P      = (float*)alloc((size_t)4 * n * 64 * 4);  // partials; plane 0 = H0
    float* H2a    = (float*)alloc((size_t)n * 32 * 4);
    float* H3a    = (float*)alloc((size_t)n * 16 * 4);
    (void)ws_size; (void)n_in; (void)out_size;

    init_prep_k<<<(K * 64 + 255) / 256, 256, 0, stream>>>(ei, flag, cnt, n, W1, Btw, K);
    count_deg_k<<<(E + 255) / 256, 256, 0, stream>>>(ei, E, flag, cnt, n);
    scan_blk_k<<<nb, 256, 0, stream>>>(cnt, offs, dis, btot, n);
    scan_add_k<<<nb, 256, 0, stream>>>(offs, btot, cnt, base4, n, nb);
    fill_csr_k<<<(E + 255) / 256, 256, 0, stream>>>(ei, E, flag, base4, dis, csr8, n);

    gemm1_mfma_k<<<(n / 128) * 4, 256, 0, stream>>>(x, Btw, P, n, K, K / 4);
    size_t q = (size_t)n * 64 / 4;
    reduce4_k<<<(int)((q + 255) / 256), 256, 0, stream>>>((float4*)P, q);

    prop64_gemm2_k<<<n * 16 / 256, 256, 0, stream>>>(P, offs, (const int2*)csr8, dis, b1, W2, H2a, n);
    prop32_gemm3_k<<<n * 8 / 256, 256, 0, stream>>>(H2a, offs, (const int2*)csr8, dis, b2, W3, H3a, n);
    prop_softmax_k<<<n * 4 / 256, 256, 0, stream>>>(H3a, offs, (const int2*)csr8, dis, b3, out, n);
}

// Round 19
// 332.789 us; speedup vs baseline: 55.6039x; 1.0678x over previous
//
#include <hip/hip_runtime.h>

// ---------------------------------------------------------------------------
// 3-layer GCN (PyG gcn_norm semantics) on MI355X.
// R19 = R18 (best, 355us) with:
//   - CSR contention planes 4 -> 8 (count + fill cursor): RMW serialization /2
//   - 2-way unrolled gather (dual accumulators) in prop64/prop32/prop_softmax:
//     two independent load chains hide L2 latency in the serial edge loop
// gemm1 (R16 lgkm-barrier), scans, fusions unchanged.
// ---------------------------------------------------------------------------

#define PL 8  // contention-splitting planes for cnt/cursor

typedef __attribute__((ext_vector_type(8))) short bf16x8;
typedef __attribute__((ext_vector_type(4))) float f32x4;
typedef __attribute__((ext_vector_type(4))) float fv4;

__device__ __forceinline__ float4 ldnt4(const float* p) {
    fv4 v = __builtin_nontemporal_load((const fv4*)p);
    return make_float4(v.x, v.y, v.z, v.w);
}
__device__ __forceinline__ void stnt(float* p, float v) {
    __builtin_nontemporal_store(v, p);
}

__device__ __forceinline__ unsigned cvt_pk_bf16(float a, float b) {
    unsigned r;
    asm("v_cvt_pk_bf16_f32 %0, %1, %2" : "=v"(r) : "v"(a), "v"(b));
    return r;
}

__device__ __forceinline__ void lds_barrier() {
    asm volatile("s_waitcnt lgkmcnt(0)" ::: "memory");
    __builtin_amdgcn_s_barrier();
    asm volatile("" ::: "memory");
}

__device__ __forceinline__ unsigned short f2bf_rne(float f) {
    unsigned u = __float_as_uint(f);
    unsigned r = (u + 0x7FFFu + ((u >> 16) & 1u)) >> 16;
    return (unsigned short)r;
}

// --- fused: zero cnt (PL planes) + int64-vs-int32 probe + W1 split/transpose
__global__ void init_prep_k(const int* __restrict__ ei, int* __restrict__ flag,
                            int* __restrict__ cnt, int n,
                            const float* __restrict__ W1,
                            unsigned short* __restrict__ Bt, int K) {
    int t = blockIdx.x * blockDim.x + threadIdx.x;
    if (t < PL * n) cnt[t] = 0;
    if (t == 0) {
        int f = 1;
        for (int i = 0; i < 256; ++i) {
            if (ei[2 * i + 1] != 0) { f = 0; break; }
        }
        *flag = f;
    }
    if (t < K * 64) {
        int nn = t & 63, k = t >> 6;
        float f = W1[(size_t)k * 64 + nn];
        unsigned short hi = f2bf_rne(f);
        float hf = __uint_as_float((unsigned)hi << 16);
        unsigned short lo = f2bf_rne(f - hf);
        Bt[(size_t)nn * K + k] = hi;
        Bt[(size_t)64 * K + (size_t)nn * K + k] = lo;
    }
}

__device__ __forceinline__ int edge_val(const int* __restrict__ ei, long long idx, int f64) {
    return f64 ? ei[2 * idx] : ei[(int)idx];
}

// count into plane e&(PL-1)
__global__ void count_deg_k(const int* __restrict__ ei, int E, const int* __restrict__ flag,
                            int* __restrict__ cnt, int n) {
    int e = blockIdx.x * blockDim.x + threadIdx.x;
    if (e >= E) return;
    int f = *flag;
    int c = edge_val(ei, (long long)E + e, f);
    atomicAdd(&cnt[(e & (PL - 1)) * n + c], 1);
}

// --- scan phase A: per-block exclusive scan of node totals (sum of planes)
__global__ void scan_blk_k(const int* __restrict__ cnt, int* __restrict__ offs,
                           float* __restrict__ dis, int* __restrict__ btot, int n) {
    __shared__ int sh[256];
    const int t = threadIdx.x;
    const int idx = blockIdx.x * 256 + t;
    int v = 0;
    if (idx < n) {
#pragma unroll
        for (int r = 0; r < PL; ++r) v += cnt[r * n + idx];
    }
    sh[t] = v;
    __syncthreads();
    for (int o = 1; o < 256; o <<= 1) {
        int add = (t >= o) ? sh[t - o] : 0;
        __syncthreads();
        sh[t] += add;
        __syncthreads();
    }
    if (idx < n) {
        offs[idx] = sh[t] - v;
        dis[idx] = rsqrtf((float)(v + 1));  // +1: self loop
    }
    if (t == 255) btot[blockIdx.x] = sh[255];
}

// phase B: finalize offs; build per-plane cursor bases
__global__ void scan_add_k(int* __restrict__ offs, const int* __restrict__ btot,
                           const int* __restrict__ cnt, int* __restrict__ basep,
                           int n, int nb) {
    __shared__ int base_sh, tot_sh;
    const int t = threadIdx.x;
    if (t == 0) {
        int base = 0, tot = 0;
        for (int i = 0; i < nb; ++i) {
            int v = btot[i];
            if (i < (int)blockIdx.x) base += v;
            tot += v;
        }
        base_sh = base;
        tot_sh = tot;
    }
    __syncthreads();
    int idx = blockIdx.x * 256 + t;
    if (idx < n) {
        int o = offs[idx] + base_sh;
        offs[idx] = o;
        int b = o;
#pragma unroll
        for (int r = 0; r < PL; ++r) {
            basep[r * n + idx] = b;
            b += cnt[r * n + idx];
        }
    }
    if (blockIdx.x == 0 && t == 0) offs[n] = tot_sh;
}

// fill packed CSR records: csr8[pos] = (f32bits(w)<<32) | src
__global__ void fill_csr_k(const int* __restrict__ ei, int E, const int* __restrict__ flag,
                           int* __restrict__ basep,
                           const float* __restrict__ dis,
                           unsigned long long* __restrict__ csr8, int n) {
    int e = blockIdx.x * blockDim.x + threadIdx.x;
    if (e >= E) return;
    int f = *flag;
    int r = edge_val(ei, (long long)e, f);
    int c = edge_val(ei, (long long)E + e, f);
    int pos = atomicAdd(&basep[(e & (PL - 1)) * n + c], 1);
    float w = dis[r] * dis[c];
    unsigned long long rec = ((unsigned long long)__float_as_uint(w) << 32) | (unsigned)r;
    csr8[pos] = rec;
}

// --- GEMM1 (R16 exact): BM=128, BK=32, K-split x4, lgkm-only barriers.
__global__ __launch_bounds__(256) void gemm1_mfma_k(
    const float* __restrict__ A, const unsigned short* __restrict__ Bt,
    float* __restrict__ P, int n, int K, int kchunk) {
    __shared__ unsigned short As[2][128][40];
    const int tid = threadIdx.x;
    const int lane = tid & 63;
    const int wid = tid >> 6;
    const int wm = wid >> 1, wn = wid & 1;
    const int lrow = lane & 15, lkh = lane >> 4;
    const int bid = blockIdx.x;
    const int by = (bid & 7) >> 1;
    const int bx = ((bid >> 3) << 1) | (bid & 1);
    const int bm = bx * 128;
    const int k0 = by * kchunk;
    const int iters = kchunk / 32;

    const unsigned short* Bh = Bt;
    const unsigned short* Bl = Bt + (size_t)64 * K;

    f32x4 acc[4][2] = {};
    float4 st[4];

    auto loadA = [&](int kt) {
#pragma unroll
        for (int i = 0; i < 4; ++i) {
            int v = tid + i * 256;
            int r = v >> 3, c = (v & 7) * 4;
            st[i] = ldnt4(A + (size_t)(bm + r) * K + k0 + kt * 32 + c);
        }
    };

    loadA(0);
    for (int kt = 0; kt < iters; ++kt) {
        bf16x8 bh[2], bl[2];
#pragma unroll
        for (int nf = 0; nf < 2; ++nf) {
            int brow = wn * 32 + nf * 16 + lrow;
            size_t bo = (size_t)brow * K + k0 + kt * 32 + lkh * 8;
            bh[nf] = *(const bf16x8*)(Bh + bo);
            bl[nf] = *(const bf16x8*)(Bl + bo);
        }
#pragma unroll
        for (int i = 0; i < 4; ++i) {
            int v = tid + i * 256;
            int r = v >> 3, c = (v & 7) * 4;
            float f0 = st[i].x, f1 = st[i].y, f2 = st[i].z, f3 = st[i].w;
            unsigned h01 = cvt_pk_bf16(f0, f1);
            unsigned h23 = cvt_pk_bf16(f2, f3);
            float r0 = f0 - __uint_as_float(h01 << 16);
            float r1 = f1 - __uint_as_float(h01 & 0xFFFF0000u);
            float r2 = f2 - __uint_as_float(h23 << 16);
            float r3 = f3 - __uint_as_float(h23 & 0xFFFF0000u);
            unsigned l01 = cvt_pk_bf16(r0, r1);
            unsigned l23 = cvt_pk_bf16(r2, r3);
            *(uint2*)&As[0][r][c] = make_uint2(h01, h23);
            *(uint2*)&As[1][r][c] = make_uint2(l01, l23);
        }
        lds_barrier();
        if (kt + 1 < iters) loadA(kt + 1);
        bf16x8 ah[4], al[4];
#pragma unroll
        for (int mf = 0; mf < 4; ++mf) {
            int row = wm * 64 + mf * 16 + lrow;
            ah[mf] = *(const bf16x8*)&As[0][row][lkh * 8];
            al[mf] = *(const bf16x8*)&As[1][row][lkh * 8];
        }
#pragma unroll
        for (int mf = 0; mf < 4; ++mf)
#pragma unroll
            for (int nf = 0; nf < 2; ++nf) {
                acc[mf][nf] = __builtin_amdgcn_mfma_f32_16x16x32_bf16(ah[mf], bh[nf], acc[mf][nf], 0, 0, 0);
                acc[mf][nf] = __builtin_amdgcn_mfma_f32_16x16x32_bf16(al[mf], bh[nf], acc[mf][nf], 0, 0, 0);
                acc[mf][nf] = __builtin_amdgcn_mfma_f32_16x16x32_bf16(ah[mf], bl[nf], acc[mf][nf], 0, 0, 0);
            }
        lds_barrier();
    }
    float* out = P + (size_t)by * n * 64;
#pragma unroll
    for (int mf = 0; mf < 4; ++mf)
#pragma unroll
        for (int nf = 0; nf < 2; ++nf)
#pragma unroll
            for (int j = 0; j < 4; ++j) {
                int row = bm + wm * 64 + mf * 16 + lkh * 4 + j;
                int col = wn * 32 + nf * 16 + lrow;
                stnt(out + (size_t)row * 64 + col, acc[mf][nf][j]);
            }
}

__global__ void reduce4_k(float4* __restrict__ p, size_t q) {
    size_t i = (size_t)blockIdx.x * blockDim.x + threadIdx.x;
    if (i >= q) return;
    float4 a = p[i];
#pragma unroll
    for (int z = 1; z < 4; ++z) {
        float4 b = ldnt4((const float*)(p + i + (size_t)z * q));
        a.x += b.x; a.y += b.y; a.z += b.z; a.w += b.w;
    }
    p[i] = a;
}

// --- fused: H1 = relu(Agg(H0)+b1) ; H2a = H1 @ W2.  16 thr/node.
__global__ __launch_bounds__(256) void prop64_gemm2_k(
    const float* __restrict__ h, const int* __restrict__ offs,
    const int2* __restrict__ csr8,
    const float* __restrict__ dis, const float* __restrict__ b1,
    const float* __restrict__ W2, float* __restrict__ H2a, int n) {
    __shared__ float Ws[64 * 32];
    __shared__ float rows[16][68];
    const int tid = threadIdx.x;
    for (int i = tid; i < 64 * 32; i += 256) Ws[i] = W2[i];
    const int t = blockIdx.x * 256 + tid;
    const int node = t >> 4, q = t & 15, nl = tid >> 4;
    float4 a0 = make_float4(0.f, 0.f, 0.f, 0.f);
    float4 a1 = make_float4(0.f, 0.f, 0.f, 0.f);
    int p0 = offs[node], p1 = offs[node + 1];
    int p = p0;
    for (; p + 1 < p1; p += 2) {
        int2 ra = csr8[p], rb = csr8[p + 1];
        float wa = __int_as_float(ra.y), wb = __int_as_float(rb.y);
        float4 ha = *(const float4*)(h + (size_t)ra.x * 64 + q * 4);
        float4 hb = *(const float4*)(h + (size_t)rb.x * 64 + q * 4);
        a0.x = fmaf(wa, ha.x, a0.x); a0.y = fmaf(wa, ha.y, a0.y);
        a0.z = fmaf(wa, ha.z, a0.z); a0.w = fmaf(wa, ha.w, a0.w);
        a1.x = fmaf(wb, hb.x, a1.x); a1.y = fmaf(wb, hb.y, a1.y);
        a1.z = fmaf(wb, hb.z, a1.z); a1.w = fmaf(wb, hb.w, a1.w);
    }
    if (p < p1) {
        int2 ra = csr8[p];
        float wa = __int_as_float(ra.y);
        float4 ha = *(const float4*)(h + (size_t)ra.x * 64 + q * 4);
        a0.x = fmaf(wa, ha.x, a0.x); a0.y = fmaf(wa, ha.y, a0.y);
        a0.z = fmaf(wa, ha.z, a0.z); a0.w = fmaf(wa, ha.w, a0.w);
    }
    float4 acc = make_float4(a0.x + a1.x, a0.y + a1.y, a0.z + a1.z, a0.w + a1.w);
    float d = dis[node];
    float ds = d * d;
    float4 hv = *(const float4*)(h + (size_t)node * 64 + q * 4);
    float4 bv = *(const float4*)(b1 + q * 4);
    acc.x = fmaxf(fmaf(ds, hv.x, acc.x) + bv.x, 0.f);
    acc.y = fmaxf(fmaf(ds, hv.y, acc.y) + bv.y, 0.f);
    acc.z = fmaxf(fmaf(ds, hv.z, acc.z) + bv.z, 0.f);
    acc.w = fmaxf(fmaf(ds, hv.w, acc.w) + bv.w, 0.f);
    *(float4*)&rows[nl][q * 4] = acc;
    __syncthreads();
    const int c0 = q * 2;
    float s0 = 0.f, s1 = 0.f;
#pragma unroll
    for (int k = 0; k < 64; ++k) {
        float v = rows[nl][k];
        s0 = fmaf(v, Ws[k * 32 + c0], s0);
        s1 = fmaf(v, Ws[k * 32 + c0 + 1], s1);
    }
    H2a[(size_t)node * 32 + c0] = s0;
    H2a[(size_t)node * 32 + c0 + 1] = s1;
}

// --- fused: H2 = relu(Agg(H2a)+b2) ; H3a = H2 @ W3.  8 thr/node.
__global__ __launch_bounds__(256) void prop32_gemm3_k(
    const float* __restrict__ h, const int* __restrict__ offs,
    const int2* __restrict__ csr8,
    const float* __restrict__ dis, const float* __restrict__ b2,
    const float* __restrict__ W3, float* __restrict__ H3a, int n) {
    __shared__ float Ws[32 * 16];
    __shared__ float rows[32][36];
    const int tid = threadIdx.x;
    for (int i = tid; i < 32 * 16; i += 256) Ws[i] = W3[i];
    const int t = blockIdx.x * 256 + tid;
    const int node = t >> 3, q = t & 7, nl = tid >> 3;
    float4 a0 = make_float4(0.f, 0.f, 0.f, 0.f);
    float4 a1 = make_float4(0.f, 0.f, 0.f, 0.f);
    int p0 = offs[node], p1 = offs[node + 1];
    int p = p0;
    for (; p + 1 < p1; p += 2) {
        int2 ra = csr8[p], rb = csr8[p + 1];
        float wa = __int_as_float(ra.y), wb = __int_as_float(rb.y);
        float4 ha = *(const float4*)(h + (size_t)ra.x * 32 + q * 4);
        float4 hb = *(const float4*)(h + (size_t)rb.x * 32 + q * 4);
        a0.x = fmaf(wa, ha.x, a0.x); a0.y = fmaf(wa, ha.y, a0.y);
        a0.z = fmaf(wa, ha.z, a0.z); a0.w = fmaf(wa, ha.w, a0.w);
        a1.x = fmaf(wb, hb.x, a1.x); a1.y = fmaf(wb, hb.y, a1.y);
        a1.z = fmaf(wb, hb.z, a1.z); a1.w = fmaf(wb, hb.w, a1.w);
    }
    if (p < p1) {
        int2 ra = csr8[p];
        float wa = __int_as_float(ra.y);
        float4 ha = *(const float4*)(h + (size_t)ra.x * 32 + q * 4);
        a0.x = fmaf(wa, ha.x, a0.x); a0.y = fmaf(wa, ha.y, a0.y);
        a0.z = fmaf(wa, ha.z, a0.z); a0.w = fmaf(wa, ha.w, a0.w);
    }
    float4 acc = make_float4(a0.x + a1.x, a0.y + a1.y, a0.z + a1.z, a0.w + a1.w);
    float d = dis[node];
    float ds = d * d;
    float4 hv = *(const float4*)(h + (size_t)node * 32 + q * 4);
    float4 bv = *(const float4*)(b2 + q * 4);
    acc.x = fmaxf(fmaf(ds, hv.x, acc.x) + bv.x, 0.f);
    acc.y = fmaxf(fmaf(ds, hv.y, acc.y) + bv.y, 0.f);
    acc.z = fmaxf(fmaf(ds, hv.z, acc.z) + bv.z, 0.f);
    acc.w = fmaxf(fmaf(ds, hv.w, acc.w) + bv.w, 0.f);
    *(float4*)&rows[nl][q * 4] = acc;
    __syncthreads();
    const int c0 = q * 2;
    float s0 = 0.f, s1 = 0.f;
#pragma unroll
    for (int k = 0; k < 32; ++k) {
        float v = rows[nl][k];
        s0 = fmaf(v, Ws[k * 16 + c0], s0);
        s1 = fmaf(v, Ws[k * 16 + c0 + 1], s1);
    }
    H3a[(size_t)node * 16 + c0] = s0;
    H3a[(size_t)node * 16 + c0 + 1] = s1;
}

// --- final propagate (F=16) + bias + softmax, float4/thread, 4 lanes/node
__global__ void prop_softmax_k(const float* __restrict__ h, const int* __restrict__ offs,
                               const int2* __restrict__ csr8,
                               const float* __restrict__ dis, const float* __restrict__ b,
                               float* __restrict__ out, int n) {
    int t = blockIdx.x * blockDim.x + threadIdx.x;
    int node = t >> 2, q = t & 3;
    if (node >= n) return;
    float4 a0 = make_float4(0.f, 0.f, 0.f, 0.f);
    float4 a1 = make_float4(0.f, 0.f, 0.f, 0.f);
    int p0 = offs[node], p1 = offs[node + 1];
    int p = p0;
    for (; p + 1 < p1; p += 2) {
        int2 ra = csr8[p], rb = csr8[p + 1];
        float wa = __int_as_float(ra.y), wb = __int_as_float(rb.y);
        float4 ha = *(const float4*)(h + (size_t)ra.x * 16 + q * 4);
        float4 hb = *(const float4*)(h + (size_t)rb.x * 16 + q * 4);
        a0.x = fmaf(wa, ha.x, a0.x); a0.y = fmaf(wa, ha.y, a0.y);
        a0.z = fmaf(wa, ha.z, a0.z); a0.w = fmaf(wa, ha.w, a0.w);
        a1.x = fmaf(wb, hb.x, a1.x); a1.y = fmaf(wb, hb.y, a1.y);
        a1.z = fmaf(wb, hb.z, a1.z); a1.w = fmaf(wb, hb.w, a1.w);
    }
    if (p < p1) {
        int2 ra = csr8[p];
        float wa = __int_as_float(ra.y);
        float4 ha = *(const float4*)(h + (size_t)ra.x * 16 + q * 4);
        a0.x = fmaf(wa, ha.x, a0.x); a0.y = fmaf(wa, ha.y, a0.y);
        a0.z = fmaf(wa, ha.z, a0.z); a0.w = fmaf(wa, ha.w, a0.w);
    }
    float4 acc = make_float4(a0.x + a1.x, a0.y + a1.y, a0.z + a1.z, a0.w + a1.w);
    float d = dis[node];
    float ds = d * d;
    float4 hv = *(const float4*)(h + (size_t)node * 16 + q * 4);
    float4 bv = *(const float4*)(b + q * 4);
    acc.x = fmaf(ds, hv.x, acc.x) + bv.x;
    acc.y = fmaf(ds, hv.y, acc.y) + bv.y;
    acc.z = fmaf(ds, hv.z, acc.z) + bv.z;
    acc.w = fmaf(ds, hv.w, acc.w) + bv.w;
    float m = fmaxf(fmaxf(acc.x, acc.y), fmaxf(acc.z, acc.w));
    m = fmaxf(m, __shfl_xor(m, 1));
    m = fmaxf(m, __shfl_xor(m, 2));
    float4 e;
    e.x = __expf(acc.x - m);
    e.y = __expf(acc.y - m);
    e.z = __expf(acc.z - m);
    e.w = __expf(acc.w - m);
    float s = e.x + e.y + e.z + e.w;
    s += __shfl_xor(s, 1);
    s += __shfl_xor(s, 2);
    float inv = 1.f / s;
    e.x *= inv; e.y *= inv; e.z *= inv; e.w *= inv;
    *(float4*)(out + (size_t)node * 16 + q * 4) = e;
}

extern "C" void kernel_launch(void* const* d_in, const int* in_sizes, int n_in,
                              void* d_out, int out_size, void* d_ws, size_t ws_size,
                              hipStream_t stream) {
    const float* x  = (const float*)d_in[0];
    const int*   ei = (const int*)d_in[1];
    const float* W1 = (const float*)d_in[2];
    const float* b1 = (const float*)d_in[3];
    const float* W2 = (const float*)d_in[4];
    const float* b2 = (const float*)d_in[5];
    const float* W3 = (const float*)d_in[6];
    const float* b3 = (const float*)d_in[7];
    float* out = (float*)d_out;

    const int n = in_sizes[2] / 64;
    const int K = in_sizes[0] / n;
    const int E = in_sizes[1] / 2;
    const int nb = (n + 255) / 256;

    char* ws = (char*)d_ws;
    size_t off = 0;
    auto alloc = [&](size_t bytes) {
        char* p = ws + off;
        off = (off + bytes + 255) & ~(size_t)255;
        return p;
    };
    int*   flag   = (int*)  alloc(4);
    int*   cnt    = (int*)  alloc((size_t)PL * n * 4);
    int*   basep  = (int*)  alloc((size_t)PL * n * 4);
    int*   offs   = (int*)  alloc((size_t)(n + 1) * 4);
    int*   btot   = (int*)  alloc((size_t)nb * 4);
    float* dis    = (float*)alloc((size_t)n * 4);
    unsigned long long* csr8 = (unsigned long long*)alloc((size_t)E * 8);
    unsigned short* Btw = (unsigned short*)alloc((size_t)2 * 64 * K * 2);
    float* P      = (float*)alloc((size_t)4 * n * 64 * 4);  // partials; plane 0 = H0
    float* H2a    = (float*)alloc((size_t)n * 32 * 4);
    float* H3a    = (float*)alloc((size_t)n * 16 * 4);
    (void)ws_size; (void)n_in; (void)out_size;

    init_prep_k<<<(K * 64 + 255) / 256, 256, 0, stream>>>(ei, flag, cnt, n, W1, Btw, K);
    count_deg_k<<<(E + 255) / 256, 256, 0, stream>>>(ei, E, flag, cnt, n);
    scan_blk_k<<<nb, 256, 0, stream>>>(cnt, offs, dis, btot, n);
    scan_add_k<<<nb, 256, 0, stream>>>(offs, btot, cnt, basep, n, nb);
    fill_csr_k<<<(E + 255) / 256, 256, 0, stream>>>(ei, E, flag, basep, dis, csr8, n);

    gemm1_mfma_k<<<(n / 128) * 4, 256, 0, stream>>>(x, Btw, P, n, K, K / 4);
    size_t q = (size_t)n * 64 / 4;
    reduce4_k<<<(int)((q + 255) / 256), 256, 0, stream>>>((float4*)P, q);

    prop64_gemm2_k<<<n * 16 / 256, 256, 0, stream>>>(P, offs, (const int2*)csr8, dis, b1, W2, H2a, n);
    prop32_gemm3_k<<<n * 8 / 256, 256, 0, stream>>>(H2a, offs, (const int2*)csr8, dis, b2, W3, H3a, n);
    prop_softmax_k<<<n * 4 / 256, 256, 0, stream>>>(H3a, offs, (const int2*)csr8, dis, b3, out, n);
}

// Round 21
// 322.519 us; speedup vs baseline: 57.3746x; 1.0318x over previous
//
#include <hip/hip_runtime.h>

// ---------------------------------------------------------------------------
// 3-layer GCN (PyG gcn_norm semantics) on MI355X.
// R21 = R20 with the init_prep_k LAUNCH-GRID BUG fixed: R20 launched only
// PL*n threads (262K) but the W1 split needs K*64 (1.05M) -> 3/4 of Bt was
// stale, absmax 4.4e-3. Grid now covers max(PL*n, K*64).
//   - CSR contention planes 16 (count + fill cursor)
//   - gather unroll 4 (quad accumulators) in prop64/prop32/prop_softmax
// gemm1 (R16 lgkm-barrier), scans, fusions unchanged.
// ---------------------------------------------------------------------------

#define PL 16  // contention-splitting planes for cnt/cursor

typedef __attribute__((ext_vector_type(8))) short bf16x8;
typedef __attribute__((ext_vector_type(4))) float f32x4;
typedef __attribute__((ext_vector_type(4))) float fv4;

__device__ __forceinline__ float4 ldnt4(const float* p) {
    fv4 v = __builtin_nontemporal_load((const fv4*)p);
    return make_float4(v.x, v.y, v.z, v.w);
}
__device__ __forceinline__ void stnt(float* p, float v) {
    __builtin_nontemporal_store(v, p);
}

__device__ __forceinline__ unsigned cvt_pk_bf16(float a, float b) {
    unsigned r;
    asm("v_cvt_pk_bf16_f32 %0, %1, %2" : "=v"(r) : "v"(a), "v"(b));
    return r;
}

__device__ __forceinline__ void lds_barrier() {
    asm volatile("s_waitcnt lgkmcnt(0)" ::: "memory");
    __builtin_amdgcn_s_barrier();
    asm volatile("" ::: "memory");
}

__device__ __forceinline__ unsigned short f2bf_rne(float f) {
    unsigned u = __float_as_uint(f);
    unsigned r = (u + 0x7FFFu + ((u >> 16) & 1u)) >> 16;
    return (unsigned short)r;
}

// --- fused: zero cnt (PL planes) + int64-vs-int32 probe + W1 split/transpose
__global__ void init_prep_k(const int* __restrict__ ei, int* __restrict__ flag,
                            int* __restrict__ cnt, int n,
                            const float* __restrict__ W1,
                            unsigned short* __restrict__ Bt, int K) {
    int t = blockIdx.x * blockDim.x + threadIdx.x;
    if (t < PL * n) cnt[t] = 0;
    if (t == 0) {
        int f = 1;
        for (int i = 0; i < 256; ++i) {
            if (ei[2 * i + 1] != 0) { f = 0; break; }
        }
        *flag = f;
    }
    if (t < K * 64) {
        int nn = t & 63, k = t >> 6;
        float f = W1[(size_t)k * 64 + nn];
        unsigned short hi = f2bf_rne(f);
        float hf = __uint_as_float((unsigned)hi << 16);
        unsigned short lo = f2bf_rne(f - hf);
        Bt[(size_t)nn * K + k] = hi;
        Bt[(size_t)64 * K + (size_t)nn * K + k] = lo;
    }
}

__device__ __forceinline__ int edge_val(const int* __restrict__ ei, long long idx, int f64) {
    return f64 ? ei[2 * idx] : ei[(int)idx];
}

// count into plane e&(PL-1)
__global__ void count_deg_k(const int* __restrict__ ei, int E, const int* __restrict__ flag,
                            int* __restrict__ cnt, int n) {
    int e = blockIdx.x * blockDim.x + threadIdx.x;
    if (e >= E) return;
    int f = *flag;
    int c = edge_val(ei, (long long)E + e, f);
    atomicAdd(&cnt[(e & (PL - 1)) * n + c], 1);
}

// --- scan phase A: per-block exclusive scan of node totals (sum of planes)
__global__ void scan_blk_k(const int* __restrict__ cnt, int* __restrict__ offs,
                           float* __restrict__ dis, int* __restrict__ btot, int n) {
    __shared__ int sh[256];
    const int t = threadIdx.x;
    const int idx = blockIdx.x * 256 + t;
    int v = 0;
    if (idx < n) {
#pragma unroll
        for (int r = 0; r < PL; ++r) v += cnt[r * n + idx];
    }
    sh[t] = v;
    __syncthreads();
    for (int o = 1; o < 256; o <<= 1) {
        int add = (t >= o) ? sh[t - o] : 0;
        __syncthreads();
        sh[t] += add;
        __syncthreads();
    }
    if (idx < n) {
        offs[idx] = sh[t] - v;
        dis[idx] = rsqrtf((float)(v + 1));  // +1: self loop
    }
    if (t == 255) btot[blockIdx.x] = sh[255];
}

// phase B: finalize offs; build per-plane cursor bases
__global__ void scan_add_k(int* __restrict__ offs, const int* __restrict__ btot,
                           const int* __restrict__ cnt, int* __restrict__ basep,
                           int n, int nb) {
    __shared__ int base_sh, tot_sh;
    const int t = threadIdx.x;
    if (t == 0) {
        int base = 0, tot = 0;
        for (int i = 0; i < nb; ++i) {
            int v = btot[i];
            if (i < (int)blockIdx.x) base += v;
            tot += v;
        }
        base_sh = base;
        tot_sh = tot;
    }
    __syncthreads();
    int idx = blockIdx.x * 256 + t;
    if (idx < n) {
        int o = offs[idx] + base_sh;
        offs[idx] = o;
        int b = o;
#pragma unroll
        for (int r = 0; r < PL; ++r) {
            basep[r * n + idx] = b;
            b += cnt[r * n + idx];
        }
    }
    if (blockIdx.x == 0 && t == 0) offs[n] = tot_sh;
}

// fill packed CSR records: csr8[pos] = (f32bits(w)<<32) | src
__global__ void fill_csr_k(const int* __restrict__ ei, int E, const int* __restrict__ flag,
                           int* __restrict__ basep,
                           const float* __restrict__ dis,
                           unsigned long long* __restrict__ csr8, int n) {
    int e = blockIdx.x * blockDim.x + threadIdx.x;
    if (e >= E) return;
    int f = *flag;
    int r = edge_val(ei, (long long)e, f);
    int c = edge_val(ei, (long long)E + e, f);
    int pos = atomicAdd(&basep[(e & (PL - 1)) * n + c], 1);
    float w = dis[r] * dis[c];
    unsigned long long rec = ((unsigned long long)__float_as_uint(w) << 32) | (unsigned)r;
    csr8[pos] = rec;
}

// --- GEMM1 (R16 exact): BM=128, BK=32, K-split x4, lgkm-only barriers.
__global__ __launch_bounds__(256) void gemm1_mfma_k(
    const float* __restrict__ A, const unsigned short* __restrict__ Bt,
    float* __restrict__ P, int n, int K, int kchunk) {
    __shared__ unsigned short As[2][128][40];
    const int tid = threadIdx.x;
    const int lane = tid & 63;
    const int wid = tid >> 6;
    const int wm = wid >> 1, wn = wid & 1;
    const int lrow = lane & 15, lkh = lane >> 4;
    const int bid = blockIdx.x;
    const int by = (bid & 7) >> 1;
    const int bx = ((bid >> 3) << 1) | (bid & 1);
    const int bm = bx * 128;
    const int k0 = by * kchunk;
    const int iters = kchunk / 32;

    const unsigned short* Bh = Bt;
    const unsigned short* Bl = Bt + (size_t)64 * K;

    f32x4 acc[4][2] = {};
    float4 st[4];

    auto loadA = [&](int kt) {
#pragma unroll
        for (int i = 0; i < 4; ++i) {
            int v = tid + i * 256;
            int r = v >> 3, c = (v & 7) * 4;
            st[i] = ldnt4(A + (size_t)(bm + r) * K + k0 + kt * 32 + c);
        }
    };

    loadA(0);
    for (int kt = 0; kt < iters; ++kt) {
        bf16x8 bh[2], bl[2];
#pragma unroll
        for (int nf = 0; nf < 2; ++nf) {
            int brow = wn * 32 + nf * 16 + lrow;
            size_t bo = (size_t)brow * K + k0 + kt * 32 + lkh * 8;
            bh[nf] = *(const bf16x8*)(Bh + bo);
            bl[nf] = *(const bf16x8*)(Bl + bo);
        }
#pragma unroll
        for (int i = 0; i < 4; ++i) {
            int v = tid + i * 256;
            int r = v >> 3, c = (v & 7) * 4;
            float f0 = st[i].x, f1 = st[i].y, f2 = st[i].z, f3 = st[i].w;
            unsigned h01 = cvt_pk_bf16(f0, f1);
            unsigned h23 = cvt_pk_bf16(f2, f3);
            float r0 = f0 - __uint_as_float(h01 << 16);
            float r1 = f1 - __uint_as_float(h01 & 0xFFFF0000u);
            float r2 = f2 - __uint_as_float(h23 << 16);
            float r3 = f3 - __uint_as_float(h23 & 0xFFFF0000u);
            unsigned l01 = cvt_pk_bf16(r0, r1);
            unsigned l23 = cvt_pk_bf16(r2, r3);
            *(uint2*)&As[0][r][c] = make_uint2(h01, h23);
            *(uint2*)&As[1][r][c] = make_uint2(l01, l23);
        }
        lds_barrier();
        if (kt + 1 < iters) loadA(kt + 1);
        bf16x8 ah[4], al[4];
#pragma unroll
        for (int mf = 0; mf < 4; ++mf) {
            int row = wm * 64 + mf * 16 + lrow;
            ah[mf] = *(const bf16x8*)&As[0][row][lkh * 8];
            al[mf] = *(const bf16x8*)&As[1][row][lkh * 8];
        }
#pragma unroll
        for (int mf = 0; mf < 4; ++mf)
#pragma unroll
            for (int nf = 0; nf < 2; ++nf) {
                acc[mf][nf] = __builtin_amdgcn_mfma_f32_16x16x32_bf16(ah[mf], bh[nf], acc[mf][nf], 0, 0, 0);
                acc[mf][nf] = __builtin_amdgcn_mfma_f32_16x16x32_bf16(al[mf], bh[nf], acc[mf][nf], 0, 0, 0);
                acc[mf][nf] = __builtin_amdgcn_mfma_f32_16x16x32_bf16(ah[mf], bl[nf], acc[mf][nf], 0, 0, 0);
            }
        lds_barrier();
    }
    float* out = P + (size_t)by * n * 64;
#pragma unroll
    for (int mf = 0; mf < 4; ++mf)
#pragma unroll
        for (int nf = 0; nf < 2; ++nf)
#pragma unroll
            for (int j = 0; j < 4; ++j) {
                int row = bm + wm * 64 + mf * 16 + lkh * 4 + j;
                int col = wn * 32 + nf * 16 + lrow;
                stnt(out + (size_t)row * 64 + col, acc[mf][nf][j]);
            }
}

__global__ void reduce4_k(float4* __restrict__ p, size_t q) {
    size_t i = (size_t)blockIdx.x * blockDim.x + threadIdx.x;
    if (i >= q) return;
    float4 a = p[i];
#pragma unroll
    for (int z = 1; z < 4; ++z) {
        float4 b = ldnt4((const float*)(p + i + (size_t)z * q));
        a.x += b.x; a.y += b.y; a.z += b.z; a.w += b.w;
    }
    p[i] = a;
}

// 4-chain gather macro: F = row stride (floats), acc into a0..a3
#define GATHER4(F)                                                                 \
    int p = p0;                                                                    \
    for (; p + 3 < p1; p += 4) {                                                   \
        int2 ra = csr8[p], rb = csr8[p + 1], rc = csr8[p + 2], rd = csr8[p + 3];   \
        float wa = __int_as_float(ra.y), wb = __int_as_float(rb.y);                \
        float wc = __int_as_float(rc.y), wd = __int_as_float(rd.y);                \
        float4 ha = *(const float4*)(h + (size_t)ra.x * (F) + q * 4);              \
        float4 hb = *(const float4*)(h + (size_t)rb.x * (F) + q * 4);              \
        float4 hc = *(const float4*)(h + (size_t)rc.x * (F) + q * 4);              \
        float4 hd = *(const float4*)(h + (size_t)rd.x * (F) + q * 4);              \
        a0.x = fmaf(wa, ha.x, a0.x); a0.y = fmaf(wa, ha.y, a0.y);                  \
        a0.z = fmaf(wa, ha.z, a0.z); a0.w = fmaf(wa, ha.w, a0.w);                  \
        a1.x = fmaf(wb, hb.x, a1.x); a1.y = fmaf(wb, hb.y, a1.y);                  \
        a1.z = fmaf(wb, hb.z, a1.z); a1.w = fmaf(wb, hb.w, a1.w);                  \
        a2.x = fmaf(wc, hc.x, a2.x); a2.y = fmaf(wc, hc.y, a2.y);                  \
        a2.z = fmaf(wc, hc.z, a2.z); a2.w = fmaf(wc, hc.w, a2.w);                  \
        a3.x = fmaf(wd, hd.x, a3.x); a3.y = fmaf(wd, hd.y, a3.y);                  \
        a3.z = fmaf(wd, hd.z, a3.z); a3.w = fmaf(wd, hd.w, a3.w);                  \
    }                                                                              \
    for (; p < p1; ++p) {                                                          \
        int2 ra = csr8[p];                                                         \
        float wa = __int_as_float(ra.y);                                           \
        float4 ha = *(const float4*)(h + (size_t)ra.x * (F) + q * 4);              \
        a0.x = fmaf(wa, ha.x, a0.x); a0.y = fmaf(wa, ha.y, a0.y);                  \
        a0.z = fmaf(wa, ha.z, a0.z); a0.w = fmaf(wa, ha.w, a0.w);                  \
    }                                                                              \
    float4 acc = make_float4(a0.x + a1.x + a2.x + a3.x, a0.y + a1.y + a2.y + a3.y, \
                             a0.z + a1.z + a2.z + a3.z, a0.w + a1.w + a2.w + a3.w);

// --- fused: H1 = relu(Agg(H0)+b1) ; H2a = H1 @ W2.  16 thr/node.
__global__ __launch_bounds__(256) void prop64_gemm2_k(
    const float* __restrict__ h, const int* __restrict__ offs,
    const int2* __restrict__ csr8,
    const float* __restrict__ dis, const float* __restrict__ b1,
    const float* __restrict__ W2, float* __restrict__ H2a, int n) {
    __shared__ float Ws[64 * 32];
    __shared__ float rows[16][68];
    const int tid = threadIdx.x;
    for (int i = tid; i < 64 * 32; i += 256) Ws[i] = W2[i];
    const int t = blockIdx.x * 256 + tid;
    const int node = t >> 4, q = t & 15, nl = tid >> 4;
    float4 a0 = make_float4(0.f, 0.f, 0.f, 0.f), a1 = a0, a2 = a0, a3 = a0;
    int p0 = offs[node], p1 = offs[node + 1];
    GATHER4(64)
    float d = dis[node];
    float ds = d * d;
    float4 hv = *(const float4*)(h + (size_t)node * 64 + q * 4);
    float4 bv = *(const float4*)(b1 + q * 4);
    acc.x = fmaxf(fmaf(ds, hv.x, acc.x) + bv.x, 0.f);
    acc.y = fmaxf(fmaf(ds, hv.y, acc.y) + bv.y, 0.f);
    acc.z = fmaxf(fmaf(ds, hv.z, acc.z) + bv.z, 0.f);
    acc.w = fmaxf(fmaf(ds, hv.w, acc.w) + bv.w, 0.f);
    *(float4*)&rows[nl][q * 4] = acc;
    __syncthreads();
    const int c0 = q * 2;
    float s0 = 0.f, s1 = 0.f;
#pragma unroll
    for (int k = 0; k < 64; ++k) {
        float v = rows[nl][k];
        s0 = fmaf(v, Ws[k * 32 + c0], s0);
        s1 = fmaf(v, Ws[k * 32 + c0 + 1], s1);
    }
    H2a[(size_t)node * 32 + c0] = s0;
    H2a[(size_t)node * 32 + c0 + 1] = s1;
}

// --- fused: H2 = relu(Agg(H2a)+b2) ; H3a = H2 @ W3.  8 thr/node.
__global__ __launch_bounds__(256) void prop32_gemm3_k(
    const float* __restrict__ h, const int* __restrict__ offs,
    const int2* __restrict__ csr8,
    const float* __restrict__ dis, const float* __restrict__ b2,
    const float* __restrict__ W3, float* __restrict__ H3a, int n) {
    __shared__ float Ws[32 * 16];
    __shared__ float rows[32][36];
    const int tid = threadIdx.x;
    for (int i = tid; i < 32 * 16; i += 256) Ws[i] = W3[i];
    const int t = blockIdx.x * 256 + tid;
    const int node = t >> 3, q = t & 7, nl = tid >> 3;
    float4 a0 = make_float4(0.f, 0.f, 0.f, 0.f), a1 = a0, a2 = a0, a3 = a0;
    int p0 = offs[node], p1 = offs[node + 1];
    GATHER4(32)
    float d = dis[node];
    float ds = d * d;
    float4 hv = *(const float4*)(h + (size_t)node * 32 + q * 4);
    float4 bv = *(const float4*)(b2 + q * 4);
    acc.x = fmaxf(fmaf(ds, hv.x, acc.x) + bv.x, 0.f);
    acc.y = fmaxf(fmaf(ds, hv.y, acc.y) + bv.y, 0.f);
    acc.z = fmaxf(fmaf(ds, hv.z, acc.z) + bv.z, 0.f);
    acc.w = fmaxf(fmaf(ds, hv.w, acc.w) + bv.w, 0.f);
    *(float4*)&rows[nl][q * 4] = acc;
    __syncthreads();
    const int c0 = q * 2;
    float s0 = 0.f, s1 = 0.f;
#pragma unroll
    for (int k = 0; k < 32; ++k) {
        float v = rows[nl][k];
        s0 = fmaf(v, Ws[k * 16 + c0], s0);
        s1 = fmaf(v, Ws[k * 16 + c0 + 1], s1);
    }
    H3a[(size_t)node * 16 + c0] = s0;
    H3a[(size_t)node * 16 + c0 + 1] = s1;
}

// --- final propagate (F=16) + bias + softmax, float4/thread, 4 lanes/node
__global__ void prop_softmax_k(const float* __restrict__ h, const int* __restrict__ offs,
                               const int2* __restrict__ csr8,
                               const float* __restrict__ dis, const float* __restrict__ b,
                               float* __restrict__ out, int n) {
    int t = blockIdx.x * blockDim.x + threadIdx.x;
    int node = t >> 2, q = t & 3;
    if (node >= n) return;
    float4 a0 = make_float4(0.f, 0.f, 0.f, 0.f), a1 = a0, a2 = a0, a3 = a0;
    int p0 = offs[node], p1 = offs[node + 1];
    GATHER4(16)
    float d = dis[node];
    float ds = d * d;
    float4 hv = *(const float4*)(h + (size_t)node * 16 + q * 4);
    float4 bv = *(const float4*)(b + q * 4);
    acc.x = fmaf(ds, hv.x, acc.x) + bv.x;
    acc.y = fmaf(ds, hv.y, acc.y) + bv.y;
    acc.z = fmaf(ds, hv.z, acc.z) + bv.z;
    acc.w = fmaf(ds, hv.w, acc.w) + bv.w;
    float m = fmaxf(fmaxf(acc.x, acc.y), fmaxf(acc.z, acc.w));
    m = fmaxf(m, __shfl_xor(m, 1));
    m = fmaxf(m, __shfl_xor(m, 2));
    float4 e;
    e.x = __expf(acc.x - m);
    e.y = __expf(acc.y - m);
    e.z = __expf(acc.z - m);
    e.w = __expf(acc.w - m);
    float s = e.x + e.y + e.z + e.w;
    s += __shfl_xor(s, 1);
    s += __shfl_xor(s, 2);
    float inv = 1.f / s;
    e.x *= inv; e.y *= inv; e.z *= inv; e.w *= inv;
    *(float4*)(out + (size_t)node * 16 + q * 4) = e;
}

extern "C" void kernel_launch(void* const* d_in, const int* in_sizes, int n_in,
                              void* d_out, int out_size, void* d_ws, size_t ws_size,
                              hipStream_t stream) {
    const float* x  = (const float*)d_in[0];
    const int*   ei = (const int*)d_in[1];
    const float* W1 = (const float*)d_in[2];
    const float* b1 = (const float*)d_in[3];
    const float* W2 = (const float*)d_in[4];
    const float* b2 = (const float*)d_in[5];
    const float* W3 = (const float*)d_in[6];
    const float* b3 = (const float*)d_in[7];
    float* out = (float*)d_out;

    const int n = in_sizes[2] / 64;
    const int K = in_sizes[0] / n;
    const int E = in_sizes[1] / 2;
    const int nb = (n + 255) / 256;

    char* ws = (char*)d_ws;
    size_t off = 0;
    auto alloc = [&](size_t bytes) {
        char* p = ws + off;
        off = (off + bytes + 255) & ~(size_t)255;
        return p;
    };
    int*   flag   = (int*)  alloc(4);
    int*   cnt    = (int*)  alloc((size_t)PL * n * 4);
    int*   basep  = (int*)  alloc((size_t)PL * n * 4);
    int*   offs   = (int*)  alloc((size_t)(n + 1) * 4);
    int*   btot   = (int*)  alloc((size_t)nb * 4);
    float* dis    = (float*)alloc((size_t)n * 4);
    unsigned long long* csr8 = (unsigned long long*)alloc((size_t)E * 8);
    unsigned short* Btw = (unsigned short*)alloc((size_t)2 * 64 * K * 2);
    float* P      = (float*)alloc((size_t)4 * n * 64 * 4);  // partials; plane 0 = H0
    float* H2a    = (float*)alloc((size_t)n * 32 * 4);
    float* H3a    = (float*)alloc((size_t)n * 16 * 4);
    (void)ws_size; (void)n_in; (void)out_size;

    // grid must cover BOTH the PL*n cnt-zeroing AND the K*64 W1 split
    int init_threads = (PL * n > K * 64) ? PL * n : K * 64;
    init_prep_k<<<(init_threads + 255) / 256, 256, 0, stream>>>(ei, flag, cnt, n, W1, Btw, K);
    count_deg_k<<<(E + 255) / 256, 256, 0, stream>>>(ei, E, flag, cnt, n);
    scan_blk_k<<<nb, 256, 0, stream>>>(cnt, offs, dis, btot, n);
    scan_add_k<<<nb, 256, 0, stream>>>(offs, btot, cnt, basep, n, nb);
    fill_csr_k<<<(E + 255) / 256, 256, 0, stream>>>(ei, E, flag, basep, dis, csr8, n);

    gemm1_mfma_k<<<(n / 128) * 4, 256, 0, stream>>>(x, Btw, P, n, K, K / 4);
    size_t q = (size_t)n * 64 / 4;
    reduce4_k<<<(int)((q + 255) / 256), 256, 0, stream>>>((float4*)P, q);

    prop64_gemm2_k<<<n * 16 / 256, 256, 0, stream>>>(P, offs, (const int2*)csr8, dis, b1, W2, H2a, n);
    prop32_gemm3_k<<<n * 8 / 256, 256, 0, stream>>>(H2a, offs, (const int2*)csr8, dis, b2, W3, H3a, n);
    prop_softmax_k<<<n * 4 / 256, 256, 0, stream>>>(H3a, offs, (const int2*)csr8, dis, b3, out, n);
}